// Round 6
// baseline (518.727 us; speedup 1.0000x reference)
//
#include <hip/hip_runtime.h>

typedef __bf16 bf16_t;
typedef bf16_t bf16x8 __attribute__((ext_vector_type(8)));
typedef float f32x4 __attribute__((ext_vector_type(4)));

#define DEV static __device__ __forceinline__

constexpr float kBnScale = 0.999995000037499375f;  // 1/sqrt(1+1e-5)

DEV unsigned short f2bf(float f) {
  unsigned u = __builtin_bit_cast(unsigned, f);
  u += 0x7fffu + ((u >> 16) & 1u);
  return (unsigned short)(u >> 16);
}
DEV float bf2f(unsigned short s) {
  return __builtin_bit_cast(float, ((unsigned)s) << 16);
}
DEV f32x4 mfma16(bf16x8 a, bf16x8 b, f32x4 c) {
  return __builtin_amdgcn_mfma_f32_16x16x32_bf16(a, b, c, 0, 0, 0);
}
DEV unsigned swz(unsigned byteoff, unsigned row) { return byteoff ^ ((row & 7u) << 4); }

// ---------------------------------------------------------------- merged pre-pass:
// blocks [0,16384): adjacency -> ELL + dinv (float4 scan, XCD-chunked)
// blocks [16384,16448): LN vector hv + hw0s = (hv@gW0)*bnScale*bng0
// blocks [16448,16928): weights -> bf16 n-major
__global__ __launch_bounds__(256) void k_pre(
    const float* __restrict__ adj, unsigned short* __restrict__ cols,
    int* __restrict__ cnt, float* __restrict__ dinv,
    const float* __restrict__ x, const float* __restrict__ fi,
    const float* __restrict__ Win, const float* __restrict__ bin,
    const float* __restrict__ lng, const float* __restrict__ lnb,
    const float* __restrict__ gW, const float* __restrict__ bng,
    float* __restrict__ hv, float* __restrict__ hw0s,
    const float* __restrict__ Wqkv, const float* __restrict__ Wo,
    const float* __restrict__ Wout,
    unsigned short* __restrict__ WqkvB, unsigned short* __restrict__ WoB,
    unsigned short* __restrict__ gWB, unsigned short* __restrict__ WoutB) {
  const int bid = blockIdx.x;
  if (bid < 16384) {
    const int c4 = (bid & 7) * 2048 + (bid >> 3);  // XCD-chunked
    const int w = threadIdx.x >> 6, lane = threadIdx.x & 63;
    const long row = (long)c4 * 4 + w;
    const float* ap = adj + row * 1024;
    unsigned short* cp = cols + row * 128;
    int c = 0;
#pragma unroll
    for (int it = 0; it < 4; ++it) {
      const float4 v4 = *(const float4*)(ap + it * 256 + lane * 4);
      const float vv[4] = {v4.x, v4.y, v4.z, v4.w};
#pragma unroll
      for (int j = 0; j < 4; ++j) {
        const unsigned long long m = __ballot(vv[j] != 0.0f);
        const int pos = c + __popcll(m & ((1ull << lane) - 1ull));
        if (vv[j] != 0.0f && pos < 128) cp[pos] = (unsigned short)(it * 256 + lane * 4 + j);
        c += __popcll(m);
      }
    }
    if (lane == 0) {
      cnt[row] = c;
      dinv[row] = 1.0f / sqrtf((float)(c + 1));
    }
  } else if (bid < 16448) {
    __shared__ float sred[2], sred2[2], shv[128];
    const int bs = bid - 16384, t = threadIdx.x;
    float accv = 0.f, d = 0.f;
    if (t < 128) {
      accv = bin[t];
      for (int f = 0; f < 64; ++f) accv += x[bs * 64 + f] * fi[f] * Win[f * 128 + t];
      float ssum = accv;
      for (int m = 1; m < 64; m <<= 1) ssum += __shfl_xor(ssum, m);
      if ((t & 63) == 0) sred[t >> 6] = ssum;
    }
    __syncthreads();
    const float mu = (sred[0] + sred[1]) * (1.0f / 128.0f);
    if (t < 128) {
      d = accv - mu;
      float vs = d * d;
      for (int m = 1; m < 64; m <<= 1) vs += __shfl_xor(vs, m);
      if ((t & 63) == 0) sred2[t >> 6] = vs;
    }
    __syncthreads();
    const float var = (sred2[0] + sred2[1]) * (1.0f / 128.0f);
    if (t < 128) {
      const float h = d / sqrtf(var + 1e-5f) * lng[t] + lnb[t];
      hv[bs * 128 + t] = h;
      shv[t] = h;
    }
    __syncthreads();
    if (t < 128) {
      float a2 = 0.f;
      for (int k = 0; k < 128; ++k) a2 += shv[k] * gW[k * 128 + t];
      hw0s[bs * 128 + t] = a2 * kBnScale * bng[t];
    }
  } else {
    const int i = (bid - 16448) * 256 + threadIdx.x;
    if (i < 49152) {
      WqkvB[i] = f2bf(Wqkv[i]);  // already [384][128] n-major
    } else if (i < 65536) {
      const int j = i - 49152;
      WoB[j] = f2bf(Wo[j]);      // already [128][128] n-major
    } else if (i < 114688) {
      const int j = i - 65536, l = j >> 14, r = j & 16383, n = r >> 7, k = r & 127;
      gWB[j] = f2bf(gW[(l << 14) + k * 128 + n]);  // transpose [k][n] -> [n][k]
    } else {
      const int j = i - 114688, n = j >> 7, k = j & 127;
      WoutB[j] = f2bf(Wout[k * 64 + n]);           // transpose [128][64] -> [64][128]
    }
  }
}

// ---------------------------------------------------------------- fused gather(SpMM/S_i) + QKV GEMM (3 panels, one A-stage)
// GMODE 0: A_row = S_i*hw0s[bs] + (gb*bnScale*bng + bnb), S_i = d(d + sum_nbr dinv)
// GMODE 1: A_row = BN(dinv_i*(hwp_self + sum_nbr hwp) + gb)
template <int GMODE>
__global__ __launch_bounds__(256, 2) void k_qkvA(
    const unsigned short* __restrict__ cols, const int* __restrict__ cnt,
    const float* __restrict__ dinv, const uint4* __restrict__ hwp16,
    const float* __restrict__ hw0s,
    const float* __restrict__ gb, const float* __restrict__ bng, const float* __restrict__ bnb,
    const unsigned short* __restrict__ WqkvB, const float* __restrict__ bqkv,
    unsigned short* __restrict__ qkvb) {
  __shared__ __align__(16) unsigned short Ab[128 * 128];
  __shared__ __align__(16) unsigned short Bb[128 * 128];
  const int t = threadIdx.x, lane = t & 63, w = t >> 6;
  const int g = lane >> 4, l15 = lane & 15;
  const int c = (blockIdx.x & 7) * 64 + (blockIdx.x >> 3);  // XCD-chunked
  const long cb = (long)c * 128;
  const int bs = (int)(cb >> 10);
  const long bsbase = (long)bs << 10;

  // ---- A staging via gather (wave w owns rows [w*32, w*32+32))
  for (int rr = 0; rr < 32; ++rr) {
    const int rowl = w * 32 + rr;
    const long row = cb + rowl;
    const unsigned colreg = ((const unsigned*)(cols + row * 128))[lane];
    const int cn = min(cnt[row], 128);
    const float di = dinv[row];

    if constexpr (GMODE == 0) {
      float s = 0.f;
      if (2 * lane < cn) s += dinv[bsbase + (colreg & 0xffffu)];
      if (2 * lane + 1 < cn) s += dinv[bsbase + (colreg >> 16)];
      for (int m = 1; m < 64; m <<= 1) s += __shfl_xor(s, m);
      const float S = di * (di + s);
      if (g == 0) {
        const float4 hw0 = ((const float4*)(hw0s + bs * 128))[l15 * 2];
        const float4 hw1 = ((const float4*)(hw0s + bs * 128))[l15 * 2 + 1];
        const float4 gv0 = ((const float4*)gb)[l15 * 2], gv1 = ((const float4*)gb)[l15 * 2 + 1];
        const float4 bg0 = ((const float4*)bng)[l15 * 2], bg1 = ((const float4*)bng)[l15 * 2 + 1];
        const float4 bb0 = ((const float4*)bnb)[l15 * 2], bb1 = ((const float4*)bnb)[l15 * 2 + 1];
        float o[8];
        o[0] = S * hw0.x + (gv0.x * kBnScale * bg0.x + bb0.x);
        o[1] = S * hw0.y + (gv0.y * kBnScale * bg0.y + bb0.y);
        o[2] = S * hw0.z + (gv0.z * kBnScale * bg0.z + bb0.z);
        o[3] = S * hw0.w + (gv0.w * kBnScale * bg0.w + bb0.w);
        o[4] = S * hw1.x + (gv1.x * kBnScale * bg1.x + bb1.x);
        o[5] = S * hw1.y + (gv1.y * kBnScale * bg1.y + bb1.y);
        o[6] = S * hw1.z + (gv1.z * kBnScale * bg1.z + bb1.z);
        o[7] = S * hw1.w + (gv1.w * kBnScale * bg1.w + bb1.w);
        uint4 rbits;
        rbits.x = (unsigned)f2bf(o[0]) | ((unsigned)f2bf(o[1]) << 16);
        rbits.y = (unsigned)f2bf(o[2]) | ((unsigned)f2bf(o[3]) << 16);
        rbits.z = (unsigned)f2bf(o[4]) | ((unsigned)f2bf(o[5]) << 16);
        rbits.w = (unsigned)f2bf(o[6]) | ((unsigned)f2bf(o[7]) << 16);
        *(uint4*)(Ab + (swz((unsigned)rowl * 256u + (unsigned)l15 * 16u, rowl) >> 1)) = rbits;
      }
    } else {
      float acc[8];
#pragma unroll
      for (int e = 0; e < 8; ++e) acc[e] = 0.f;
      if (g == 0) {  // self term once
        const uint4 u = hwp16[row * 16 + l15];
        const unsigned uu[4] = {u.x, u.y, u.z, u.w};
#pragma unroll
        for (int e2 = 0; e2 < 4; ++e2) {
          acc[e2 * 2] += bf2f((unsigned short)uu[e2]);
          acc[e2 * 2 + 1] += bf2f((unsigned short)(uu[e2] >> 16));
        }
      }
      const int cn4 = cn & ~3;
#pragma unroll 2
      for (int i = 0; i < cn4; i += 4) {
        const unsigned jp = __shfl(colreg, (i + g) >> 1);
        const int j = (g & 1) ? (int)(jp >> 16) : (int)(jp & 0xffffu);
        const uint4 u = hwp16[(bsbase + j) * 16 + l15];
        const unsigned uu[4] = {u.x, u.y, u.z, u.w};
#pragma unroll
        for (int e2 = 0; e2 < 4; ++e2) {
          acc[e2 * 2] += bf2f((unsigned short)uu[e2]);
          acc[e2 * 2 + 1] += bf2f((unsigned short)(uu[e2] >> 16));
        }
      }
      if (cn4 + g < cn) {
        const unsigned jp = __shfl(colreg, (cn4 + g) >> 1);
        const int j = (g & 1) ? (int)(jp >> 16) : (int)(jp & 0xffffu);
        const uint4 u = hwp16[(bsbase + j) * 16 + l15];
        const unsigned uu[4] = {u.x, u.y, u.z, u.w};
#pragma unroll
        for (int e2 = 0; e2 < 4; ++e2) {
          acc[e2 * 2] += bf2f((unsigned short)uu[e2]);
          acc[e2 * 2 + 1] += bf2f((unsigned short)(uu[e2] >> 16));
        }
      }
#pragma unroll
      for (int e = 0; e < 8; ++e) {
        acc[e] += __shfl_xor(acc[e], 16);
        acc[e] += __shfl_xor(acc[e], 32);
      }
      if (g == 0) {
        const float4 gv0 = ((const float4*)gb)[l15 * 2], gv1 = ((const float4*)gb)[l15 * 2 + 1];
        const float4 bg0 = ((const float4*)bng)[l15 * 2], bg1 = ((const float4*)bng)[l15 * 2 + 1];
        const float4 bb0 = ((const float4*)bnb)[l15 * 2], bb1 = ((const float4*)bnb)[l15 * 2 + 1];
        float o[8];
        o[0] = (di * acc[0] + gv0.x) * (kBnScale * bg0.x) + bb0.x;
        o[1] = (di * acc[1] + gv0.y) * (kBnScale * bg0.y) + bb0.y;
        o[2] = (di * acc[2] + gv0.z) * (kBnScale * bg0.z) + bb0.z;
        o[3] = (di * acc[3] + gv0.w) * (kBnScale * bg0.w) + bb0.w;
        o[4] = (di * acc[4] + gv1.x) * (kBnScale * bg1.x) + bb1.x;
        o[5] = (di * acc[5] + gv1.y) * (kBnScale * bg1.y) + bb1.y;
        o[6] = (di * acc[6] + gv1.z) * (kBnScale * bg1.z) + bb1.z;
        o[7] = (di * acc[7] + gv1.w) * (kBnScale * bg1.w) + bb1.w;
        uint4 rbits;
        rbits.x = (unsigned)f2bf(o[0]) | ((unsigned)f2bf(o[1]) << 16);
        rbits.y = (unsigned)f2bf(o[2]) | ((unsigned)f2bf(o[3]) << 16);
        rbits.z = (unsigned)f2bf(o[4]) | ((unsigned)f2bf(o[5]) << 16);
        rbits.w = (unsigned)f2bf(o[6]) | ((unsigned)f2bf(o[7]) << 16);
        *(uint4*)(Ab + (swz((unsigned)rowl * 256u + (unsigned)l15 * 16u, rowl) >> 1)) = rbits;
      }
    }
  }
  __syncthreads();

  // ---- GEMM: 3 panels, one A-stage
  const int wr = w >> 1, wc = w & 1;
  const f32x4 vzero = {0.f, 0.f, 0.f, 0.f};
#pragma unroll 1
  for (int pan = 0; pan < 3; ++pan) {
#pragma unroll
    for (int i = 0; i < 8; ++i) {
      const int f = (t + i * 256) * 8;
      const unsigned n = f >> 7, k = f & 127;
      *(uint4*)(Bb + (swz(n * 256u + k * 2u, n) >> 1)) = *(const uint4*)(WqkvB + pan * 16384 + f);
    }
    __syncthreads();
    f32x4 acc[4][4];
#pragma unroll
    for (int a = 0; a < 4; ++a)
#pragma unroll
      for (int b = 0; b < 4; ++b) acc[a][b] = vzero;
#pragma unroll
    for (int kk = 0; kk < 4; ++kk) {
      const unsigned kb = kk * 64u + (unsigned)(g << 4);
      bf16x8 af[4], bfr[4];
#pragma unroll
      for (int mt = 0; mt < 4; ++mt) {
        const unsigned row = wr * 64 + mt * 16 + l15;
        af[mt] = *(const bf16x8*)(Ab + (swz(row * 256u + kb, row) >> 1));
      }
#pragma unroll
      for (int nt = 0; nt < 4; ++nt) {
        const unsigned col = wc * 64 + nt * 16 + l15;
        bfr[nt] = *(const bf16x8*)(Bb + (swz(col * 256u + kb, col) >> 1));
      }
#pragma unroll
      for (int mt = 0; mt < 4; ++mt)
#pragma unroll
        for (int nt = 0; nt < 4; ++nt) acc[mt][nt] = mfma16(af[mt], bfr[nt], acc[mt][nt]);
    }
#pragma unroll
    for (int mt = 0; mt < 4; ++mt)
#pragma unroll
      for (int nt = 0; nt < 4; ++nt)
#pragma unroll
        for (int r = 0; r < 4; ++r) {
          const long gRow = cb + wr * 64 + mt * 16 + g * 4 + r;
          const int gCol = wc * 64 + nt * 16 + l15;
          qkvb[gRow * 384 + pan * 128 + gCol] = f2bf(acc[mt][nt][r] + bqkv[pan * 128 + gCol]);
        }
    __syncthreads();
  }
}

// ---------------------------------------------------------------- fused attn + Wo/relu/skip + chain GEMM (64 KB LDS, 2 blocks/CU)
// MODE 0: skip = hv;            chain @gW1*dinv -> hwp; write hbufb
// MODE 1: skip = hbufb;         chain @gW2*dinv -> hwp; write hbufb
// MODE 2: skip = hbufb + hv;    chain @Wout+bout, *mask -> ne (+ gpart col-sums)
template <int MODE>
__global__ __launch_bounds__(256, 2) void k_af(
    const unsigned short* __restrict__ qkv,
    const unsigned short* __restrict__ WoB, const unsigned short* __restrict__ B2,
    const float* __restrict__ bo, const float* __restrict__ hv,
    const float* __restrict__ dinv, const float* __restrict__ bout,
    const float* __restrict__ mask,
    unsigned short* __restrict__ hbufb, unsigned short* __restrict__ hwp,
    float* __restrict__ ne, float* __restrict__ gpart) {
  __shared__ __align__(16) unsigned short sm[32768];  // 64 KB
  unsigned short* Ab = sm;           // attn: vT [head][dh][node]; then aout tile; then T tile
  unsigned short* Bb = sm + 16384;   // attn: per-wave P scratch; then Wo; then B2
  const int t = threadIdx.x, lane = t & 63, hd = t >> 6;
  const int g = lane >> 4, l15 = lane & 15;
  const int c = (blockIdx.x & 7) * 64 + (blockIdx.x >> 3);  // XCD-chunked
  const long cb = (long)c * 128;
  const int bs = (int)(cb >> 10);
  const f32x4 vzero = {0.f, 0.f, 0.f, 0.f};

  // ---- stage V^T (all threads, all heads)
  {
    const int m = t >> 1, half = t & 1;
    const unsigned short* vrow = qkv + (cb + m) * 384 + 256 + half * 64;
#pragma unroll
    for (int c8 = 0; c8 < 8; ++c8) {
      const uint4 u = *(const uint4*)(vrow + c8 * 8);
      const int col0 = half * 64 + c8 * 8;
      unsigned short* vb = Ab + (col0 >> 5) * 4096;
      const int dh0 = col0 & 31;
      const unsigned short e[8] = {(unsigned short)u.x, (unsigned short)(u.x >> 16),
                                   (unsigned short)u.y, (unsigned short)(u.y >> 16),
                                   (unsigned short)u.z, (unsigned short)(u.z >> 16),
                                   (unsigned short)u.w, (unsigned short)(u.w >> 16)};
#pragma unroll
      for (int j = 0; j < 8; ++j) {
        const unsigned dh = dh0 + j;
        vb[swz(dh * 256u + (unsigned)m * 2u, dh) >> 1] = e[j];
      }
    }
  }
  bf16x8 kf[8];
#pragma unroll
  for (int nt = 0; nt < 8; ++nt)
    kf[nt] = *(const bf16x8*)(qkv + (cb + nt * 16 + l15) * 384 + 128 + hd * 32 + (g << 3));
  __syncthreads();

  const unsigned short* vbb = Ab + hd * 4096;
  unsigned short* pb = Bb + hd * 4096;
  const float SC = 0.17677669529663687f * 1.4426950408889634f;  // dh^-0.5 * log2(e)
  unsigned pk[4][2][2][2];  // packed bf16 attn-out [p][mt][nt][r-pair]

#pragma unroll 1
  for (int p = 0; p < 4; ++p) {
    bf16x8 qf[2];
#pragma unroll
    for (int mt = 0; mt < 2; ++mt)
      qf[mt] = *(const bf16x8*)(qkv + (cb + p * 32 + mt * 16 + l15) * 384 + hd * 32 + (g << 3));
    f32x4 s[2][8];
#pragma unroll
    for (int mt = 0; mt < 2; ++mt)
#pragma unroll
      for (int nt = 0; nt < 8; ++nt) s[mt][nt] = vzero;
#pragma unroll
    for (int nt = 0; nt < 8; ++nt)
#pragma unroll
      for (int mt = 0; mt < 2; ++mt) s[mt][nt] = mfma16(qf[mt], kf[nt], s[mt][nt]);

    float rinv[2][4];
#pragma unroll
    for (int mt = 0; mt < 2; ++mt) {
#pragma unroll
      for (int r = 0; r < 4; ++r) {
        float mx = s[mt][0][r];
#pragma unroll
        for (int nt = 1; nt < 8; ++nt) mx = fmaxf(mx, s[mt][nt][r]);
#pragma unroll
        for (int msk = 1; msk < 16; msk <<= 1) mx = fmaxf(mx, __shfl_xor(mx, msk));
        const unsigned qp = mt * 16 + g * 4 + r;
        float sum = 0.f;
#pragma unroll
        for (int nt = 0; nt < 8; ++nt) {
          const float e = exp2f((s[mt][nt][r] - mx) * SC);
          sum += e;
          pb[swz(qp * 256u + (nt * 16 + l15) * 2u, qp) >> 1] = f2bf(e);
        }
#pragma unroll
        for (int msk = 1; msk < 16; msk <<= 1) sum += __shfl_xor(sum, msk);
        rinv[mt][r] = 1.0f / sum;
      }
    }

    f32x4 o[2][2];
#pragma unroll
    for (int mt = 0; mt < 2; ++mt)
#pragma unroll
      for (int nt = 0; nt < 2; ++nt) o[mt][nt] = vzero;
#pragma unroll
    for (int kk = 0; kk < 4; ++kk) {
      const unsigned kb = kk * 64u + (unsigned)(g << 4);
      bf16x8 pa[2], vf[2];
#pragma unroll
      for (int mt = 0; mt < 2; ++mt) {
        const unsigned rq = mt * 16 + l15;
        pa[mt] = *(const bf16x8*)(pb + (swz(rq * 256u + kb, rq) >> 1));
      }
#pragma unroll
      for (int nt = 0; nt < 2; ++nt) {
        const unsigned dh = nt * 16 + l15;
        vf[nt] = *(const bf16x8*)(vbb + (swz(dh * 256u + kb, dh) >> 1));
      }
#pragma unroll
      for (int mt = 0; mt < 2; ++mt)
#pragma unroll
        for (int nt = 0; nt < 2; ++nt) o[mt][nt] = mfma16(pa[mt], vf[nt], o[mt][nt]);
    }
#pragma unroll
    for (int mt = 0; mt < 2; ++mt)
#pragma unroll
      for (int nt = 0; nt < 2; ++nt) {
        pk[p][mt][nt][0] = (unsigned)f2bf(o[mt][nt][0] * rinv[mt][0]) |
                           ((unsigned)f2bf(o[mt][nt][1] * rinv[mt][1]) << 16);
        pk[p][mt][nt][1] = (unsigned)f2bf(o[mt][nt][2] * rinv[mt][2]) |
                           ((unsigned)f2bf(o[mt][nt][3] * rinv[mt][3]) << 16);
      }
  }
  __syncthreads();  // attention done: Ab/Bb reusable

  // scatter attn-out -> Ab; stage Wo -> Bb
#pragma unroll
  for (int p = 0; p < 4; ++p)
#pragma unroll
    for (int mt = 0; mt < 2; ++mt)
#pragma unroll
      for (int nt = 0; nt < 2; ++nt)
#pragma unroll
        for (int rr = 0; rr < 2; ++rr) {
          const unsigned u = pk[p][mt][nt][rr];
          const unsigned row0 = p * 32 + mt * 16 + g * 4 + rr * 2;
          const unsigned col = hd * 32 + nt * 16 + l15;
          Ab[swz(row0 * 256u + col * 2u, row0) >> 1] = (unsigned short)u;
          Ab[swz((row0 + 1) * 256u + col * 2u, row0 + 1) >> 1] = (unsigned short)(u >> 16);
        }
#pragma unroll
  for (int i = 0; i < 8; ++i) {
    const int f = (t + i * 256) * 8;
    const unsigned n = f >> 7, k = f & 127;
    *(uint4*)(Bb + (swz(n * 256u + k * 2u, n) >> 1)) = *(const uint4*)(WoB + f);
  }
  __syncthreads();

  // ---- GEMM1: aout @ Wo^T
  const int wr = hd >> 1, wc = hd & 1;
  f32x4 acc[4][4];
#pragma unroll
  for (int a = 0; a < 4; ++a)
#pragma unroll
    for (int b = 0; b < 4; ++b) acc[a][b] = vzero;
#pragma unroll
  for (int kk = 0; kk < 4; ++kk) {
    const unsigned kb = kk * 64u + (unsigned)(g << 4);
    bf16x8 af[4], bfr[4];
#pragma unroll
    for (int mt = 0; mt < 4; ++mt) {
      const unsigned row = wr * 64 + mt * 16 + l15;
      af[mt] = *(const bf16x8*)(Ab + (swz(row * 256u + kb, row) >> 1));
    }
#pragma unroll
    for (int nt = 0; nt < 4; ++nt) {
      const unsigned col = wc * 64 + nt * 16 + l15;
      bfr[nt] = *(const bf16x8*)(Bb + (swz(col * 256u + kb, col) >> 1));
    }
#pragma unroll
    for (int mt = 0; mt < 4; ++mt)
#pragma unroll
      for (int nt = 0; nt < 4; ++nt) acc[mt][nt] = mfma16(af[mt], bfr[nt], acc[mt][nt]);
  }
  __syncthreads();  // done reading Ab/Bb

  // ---- epilogue1: T = skip + relu(acc + bo) -> Ab (bf16); h_new -> hbufb (MODE<2)
  {
    const float b0 = bo[wc * 64 + l15], b1 = bo[wc * 64 + 16 + l15];
    const float b2c = bo[wc * 64 + 32 + l15], b3c = bo[wc * 64 + 48 + l15];
    const float bb[4] = {b0, b1, b2c, b3c};
    float hb[4];
#pragma unroll
    for (int nt = 0; nt < 4; ++nt) hb[nt] = hv[bs * 128 + wc * 64 + nt * 16 + l15];
#pragma unroll
    for (int mt = 0; mt < 4; ++mt)
#pragma unroll
      for (int nt = 0; nt < 4; ++nt)
#pragma unroll
        for (int r = 0; r < 4; ++r) {
          const unsigned row = wr * 64 + mt * 16 + g * 4 + r;
          const long gRow = cb + row;
          const unsigned col = wc * 64 + nt * 16 + l15;
          float v = acc[mt][nt][r] + bb[nt];
          v = v > 0.f ? v : 0.f;
          if constexpr (MODE == 0) {
            v += hb[nt];
          } else {
            v += bf2f(hbufb[gRow * 128 + col]);
            if constexpr (MODE == 2) v += hb[nt];
          }
          const unsigned short vb = f2bf(v);
          if constexpr (MODE < 2) hbufb[gRow * 128 + col] = vb;
          Ab[swz(row * 256u + col * 2u, row) >> 1] = vb;
        }
  }
  // stage B2 -> Bb
  if constexpr (MODE < 2) {
#pragma unroll
    for (int i = 0; i < 8; ++i) {
      const int f = (t + i * 256) * 8;
      const unsigned n = f >> 7, k = f & 127;
      *(uint4*)(Bb + (swz(n * 256u + k * 2u, n) >> 1)) = *(const uint4*)(B2 + f);
    }
  } else {
#pragma unroll
    for (int i = 0; i < 4; ++i) {
      const int f = (t + i * 256) * 8;
      const unsigned n = f >> 7, k = f & 127;
      *(uint4*)(Bb + (swz(n * 256u + k * 2u, n) >> 1)) = *(const uint4*)(B2 + f);
    }
  }
  __syncthreads();

  // ---- GEMM2
  if constexpr (MODE < 2) {
#pragma unroll
    for (int a = 0; a < 4; ++a)
#pragma unroll
      for (int b = 0; b < 4; ++b) acc[a][b] = vzero;
#pragma unroll
    for (int kk = 0; kk < 4; ++kk) {
      const unsigned kb = kk * 64u + (unsigned)(g << 4);
      bf16x8 af[4], bfr[4];
#pragma unroll
      for (int mt = 0; mt < 4; ++mt) {
        const unsigned row = wr * 64 + mt * 16 + l15;
        af[mt] = *(const bf16x8*)(Ab + (swz(row * 256u + kb, row) >> 1));
      }
#pragma unroll
      for (int nt = 0; nt < 4; ++nt) {
        const unsigned col = wc * 64 + nt * 16 + l15;
        bfr[nt] = *(const bf16x8*)(Bb + (swz(col * 256u + kb, col) >> 1));
      }
#pragma unroll
      for (int mt = 0; mt < 4; ++mt)
#pragma unroll
        for (int nt = 0; nt < 4; ++nt) acc[mt][nt] = mfma16(af[mt], bfr[nt], acc[mt][nt]);
    }
#pragma unroll
    for (int mt = 0; mt < 4; ++mt)
#pragma unroll
      for (int nt = 0; nt < 4; ++nt)
#pragma unroll
        for (int r = 0; r < 4; ++r) {
          const long gRow = cb + wr * 64 + mt * 16 + g * 4 + r;
          const unsigned col = wc * 64 + nt * 16 + l15;
          hwp[gRow * 128 + col] = f2bf(acc[mt][nt][r] * dinv[gRow]);
        }
  } else {
    f32x4 acc2[4][2];
#pragma unroll
    for (int a = 0; a < 4; ++a)
#pragma unroll
      for (int b = 0; b < 2; ++b) acc2[a][b] = vzero;
#pragma unroll
    for (int kk = 0; kk < 4; ++kk) {
      const unsigned kb = kk * 64u + (unsigned)(g << 4);
      bf16x8 af[4], bfr[2];
#pragma unroll
      for (int mt = 0; mt < 4; ++mt) {
        const unsigned row = wr * 64 + mt * 16 + l15;
        af[mt] = *(const bf16x8*)(Ab + (swz(row * 256u + kb, row) >> 1));
      }
#pragma unroll
      for (int nt = 0; nt < 2; ++nt) {
        const unsigned col = wc * 32 + nt * 16 + l15;
        bfr[nt] = *(const bf16x8*)(Bb + (swz(col * 256u + kb, col) >> 1));
      }
#pragma unroll
      for (int mt = 0; mt < 4; ++mt)
#pragma unroll
        for (int nt = 0; nt < 2; ++nt) acc2[mt][nt] = mfma16(af[mt], bfr[nt], acc2[mt][nt]);
    }
    const float mk = mask[bs];
#pragma unroll
    for (int nt = 0; nt < 2; ++nt) {
      const unsigned col = wc * 32 + nt * 16 + l15;
      const float b2 = bout[col];
      float csum = 0.f;
#pragma unroll
      for (int mt = 0; mt < 4; ++mt)
#pragma unroll
        for (int r = 0; r < 4; ++r) {
          const long gRow = cb + wr * 64 + mt * 16 + g * 4 + r;
          const float v = (acc2[mt][nt][r] + b2) * mk;
          ne[gRow * 64 + col] = v;
          csum += v;
        }
      csum += __shfl_xor(csum, 16);
      csum += __shfl_xor(csum, 32);
      if (g == 0) gpart[((long)c * 2 + wr) * 64 + col] = csum;
    }
  }
}

// ---------------------------------------------------------------- graph mean finish: ge = sum(gpart)/1024
__global__ void k_gfin(const float* __restrict__ gpart, float* __restrict__ ge) {
  const int tid = blockIdx.x * 256 + threadIdx.x;
  if (tid >= 4096) return;
  const int bs = tid >> 6, col = tid & 63;
  float s = 0.f;
#pragma unroll
  for (int q = 0; q < 16; ++q) s += gpart[(bs * 16 + q) * 64 + col];
  ge[tid] = s * (1.0f / 1024.0f);
}

// ----------------------------------------------------------------
extern "C" void kernel_launch(void* const* d_in, const int* in_sizes, int n_in,
                              void* d_out, int out_size, void* d_ws, size_t ws_size,
                              hipStream_t stream) {
  const float* x = (const float*)d_in[0];
  const float* adj = (const float*)d_in[1];
  const float* mask = (const float*)d_in[2];
  const float* fi = (const float*)d_in[3];
  const float* Win = (const float*)d_in[4];
  const float* bin = (const float*)d_in[5];
  const float* lng = (const float*)d_in[6];
  const float* lnb = (const float*)d_in[7];
  const float* gW = (const float*)d_in[8];
  const float* gB = (const float*)d_in[9];
  const float* bng = (const float*)d_in[10];
  const float* bnb = (const float*)d_in[11];
  const float* Wqkv = (const float*)d_in[12];
  const float* bqkv = (const float*)d_in[13];
  const float* Wo = (const float*)d_in[14];
  const float* bo = (const float*)d_in[15];
  const float* Wout = (const float*)d_in[16];
  const float* bout = (const float*)d_in[17];

  char* ws = (char*)d_ws;
  float* dinv = (float*)ws;                    ws += 65536 * 4;
  int* cnt = (int*)ws;                         ws += 65536 * 4;
  float* hv = (float*)ws;                      ws += 64 * 128 * 4;
  float* hw0s = (float*)ws;                    ws += 64 * 128 * 4;
  float* gpart = (float*)ws;                   ws += 1024 * 64 * 4;
  unsigned short* WqkvB = (unsigned short*)ws; ws += 49152 * 2;
  unsigned short* WoB = (unsigned short*)ws;   ws += 16384 * 2;
  unsigned short* gWB = (unsigned short*)ws;   ws += 49152 * 2;
  unsigned short* WoutB = (unsigned short*)ws; ws += 8192 * 2;
  unsigned short* cols = (unsigned short*)ws;  ws += (size_t)65536 * 128 * 2;
  unsigned short* hbufb = (unsigned short*)ws; ws += (size_t)65536 * 128 * 2;
  unsigned short* hwp = (unsigned short*)ws;   ws += (size_t)65536 * 128 * 2;
  unsigned short* qkvb = (unsigned short*)ws;  ws += (size_t)65536 * 384 * 2;

  float* ne = (float*)d_out;
  float* ge = ne + (size_t)4194304;

  k_pre<<<16928, 256, 0, stream>>>(adj, cols, cnt, dinv, x, fi, Win, bin, lng, lnb,
                                   gW, bng, hv, hw0s, Wqkv, Wo, Wout,
                                   WqkvB, WoB, gWB, WoutB);

  // layer 0 (rank-1 GCN: dinv-gather + S*hw0s+cvec fused into A-staging)
  k_qkvA<0><<<512, 256, 0, stream>>>(cols, cnt, dinv, nullptr, hw0s,
                                     gB, bng, bnb, WqkvB, bqkv, qkvb);
  k_af<0><<<512, 256, 0, stream>>>(qkvb, WoB, gWB + 16384, bo, hv, dinv, nullptr, nullptr,
                                   hbufb, hwp, nullptr, nullptr);
  // layer 1 (SpMM gather fused into A-staging)
  k_qkvA<1><<<512, 256, 0, stream>>>(cols, cnt, dinv, (const uint4*)hwp, nullptr,
                                     gB + 128, bng + 128, bnb + 128, WqkvB, bqkv, qkvb);
  k_af<1><<<512, 256, 0, stream>>>(qkvb, WoB, gWB + 32768, bo, hv, dinv, nullptr, nullptr,
                                   hbufb, hwp, nullptr, nullptr);
  // layer 2
  k_qkvA<1><<<512, 256, 0, stream>>>(cols, cnt, dinv, (const uint4*)hwp, nullptr,
                                     gB + 256, bng + 256, bnb + 256, WqkvB, bqkv, qkvb);
  k_af<2><<<512, 256, 0, stream>>>(qkvb, WoB, WoutB, bo, hv, dinv, bout, mask,
                                   hbufb, nullptr, ne, gpart);

  k_gfin<<<16, 256, 0, stream>>>(gpart, ge);
}

// Round 7
// 348.562 us; speedup vs baseline: 1.4882x; 1.4882x over previous
//
#include <hip/hip_runtime.h>

typedef __bf16 bf16_t;
typedef bf16_t bf16x8 __attribute__((ext_vector_type(8)));
typedef float f32x4 __attribute__((ext_vector_type(4)));

#define DEV static __device__ __forceinline__

constexpr float kBnScale = 0.999995000037499375f;  // 1/sqrt(1+1e-5)

DEV unsigned short f2bf(float f) {
  unsigned u = __builtin_bit_cast(unsigned, f);
  u += 0x7fffu + ((u >> 16) & 1u);
  return (unsigned short)(u >> 16);
}
DEV float bf2f(unsigned short s) {
  return __builtin_bit_cast(float, ((unsigned)s) << 16);
}
DEV f32x4 mfma16(bf16x8 a, bf16x8 b, f32x4 c) {
  return __builtin_amdgcn_mfma_f32_16x16x32_bf16(a, b, c, 0, 0, 0);
}
DEV unsigned swz(unsigned byteoff, unsigned row) { return byteoff ^ ((row & 7u) << 4); }

// ---------------------------------------------------------------- merged pre-pass:
// blocks [0,16384): adjacency -> ELL + dinv (float4 scan, XCD-chunked)
// blocks [16384,16448): LN vector hv + hw0s = (hv@gW0)*bnScale*bng0
// blocks [16448,16928): weights -> bf16 n-major
__global__ __launch_bounds__(256) void k_pre(
    const float* __restrict__ adj, unsigned short* __restrict__ cols,
    int* __restrict__ cnt, float* __restrict__ dinv,
    const float* __restrict__ x, const float* __restrict__ fi,
    const float* __restrict__ Win, const float* __restrict__ bin,
    const float* __restrict__ lng, const float* __restrict__ lnb,
    const float* __restrict__ gW, const float* __restrict__ bng,
    float* __restrict__ hv, float* __restrict__ hw0s,
    const float* __restrict__ Wqkv, const float* __restrict__ Wo,
    const float* __restrict__ Wout,
    unsigned short* __restrict__ WqkvB, unsigned short* __restrict__ WoB,
    unsigned short* __restrict__ gWB, unsigned short* __restrict__ WoutB) {
  const int bid = blockIdx.x;
  if (bid < 16384) {
    const int c4 = (bid & 7) * 2048 + (bid >> 3);  // XCD-chunked
    const int w = threadIdx.x >> 6, lane = threadIdx.x & 63;
    const long row = (long)c4 * 4 + w;
    const float* ap = adj + row * 1024;
    unsigned short* cp = cols + row * 128;
    int c = 0;
#pragma unroll
    for (int it = 0; it < 4; ++it) {
      const float4 v4 = *(const float4*)(ap + it * 256 + lane * 4);
      const float vv[4] = {v4.x, v4.y, v4.z, v4.w};
#pragma unroll
      for (int j = 0; j < 4; ++j) {
        const unsigned long long m = __ballot(vv[j] != 0.0f);
        const int pos = c + __popcll(m & ((1ull << lane) - 1ull));
        if (vv[j] != 0.0f && pos < 128) cp[pos] = (unsigned short)(it * 256 + lane * 4 + j);
        c += __popcll(m);
      }
    }
    if (lane == 0) {
      cnt[row] = c;
      dinv[row] = 1.0f / sqrtf((float)(c + 1));
    }
  } else if (bid < 16448) {
    __shared__ float sred[2], sred2[2], shv[128];
    const int bs = bid - 16384, t = threadIdx.x;
    float accv = 0.f, d = 0.f;
    if (t < 128) {
      accv = bin[t];
      for (int f = 0; f < 64; ++f) accv += x[bs * 64 + f] * fi[f] * Win[f * 128 + t];
      float ssum = accv;
      for (int m = 1; m < 64; m <<= 1) ssum += __shfl_xor(ssum, m);
      if ((t & 63) == 0) sred[t >> 6] = ssum;
    }
    __syncthreads();
    const float mu = (sred[0] + sred[1]) * (1.0f / 128.0f);
    if (t < 128) {
      d = accv - mu;
      float vs = d * d;
      for (int m = 1; m < 64; m <<= 1) vs += __shfl_xor(vs, m);
      if ((t & 63) == 0) sred2[t >> 6] = vs;
    }
    __syncthreads();
    const float var = (sred2[0] + sred2[1]) * (1.0f / 128.0f);
    if (t < 128) {
      const float h = d / sqrtf(var + 1e-5f) * lng[t] + lnb[t];
      hv[bs * 128 + t] = h;
      shv[t] = h;
    }
    __syncthreads();
    if (t < 128) {
      float a2 = 0.f;
      for (int k = 0; k < 128; ++k) a2 += shv[k] * gW[k * 128 + t];
      hw0s[bs * 128 + t] = a2 * kBnScale * bng[t];
    }
  } else {
    const int i = (bid - 16448) * 256 + threadIdx.x;
    if (i < 49152) {
      WqkvB[i] = f2bf(Wqkv[i]);  // already [384][128] n-major
    } else if (i < 65536) {
      const int j = i - 49152;
      WoB[j] = f2bf(Wo[j]);      // already [128][128] n-major
    } else if (i < 114688) {
      const int j = i - 65536, l = j >> 14, r = j & 16383, n = r >> 7, k = r & 127;
      gWB[j] = f2bf(gW[(l << 14) + k * 128 + n]);  // transpose [k][n] -> [n][k]
    } else {
      const int j = i - 114688, n = j >> 7, k = j & 127;
      WoutB[j] = f2bf(Wout[k * 64 + n]);           // transpose [128][64] -> [64][128]
    }
  }
}

// ---------------------------------------------------------------- S_i + layer-0 GCN output: hc0 = S_i*hw0s[bs] + cvec (bf16)
__global__ __launch_bounds__(256) void k_scal2(const unsigned short* __restrict__ cols,
                                               const int* __restrict__ cnt, const float* __restrict__ dinv,
                                               const float* __restrict__ hw0s,
                                               const float* __restrict__ gb0, const float* __restrict__ bng0,
                                               const float* __restrict__ bnb0,
                                               unsigned* __restrict__ hc0) {
  int b = blockIdx.x;
  b = (b & 7) * 2048 + (b >> 3);  // XCD-chunked
  const int w = threadIdx.x >> 6, lane = threadIdx.x & 63;
  const long row = (long)b * 4 + w;
  const int cn = cnt[row] < 128 ? cnt[row] : 128;
  const long bsbase = row & ~1023L;
  const int c0 = cols[row * 128 + lane];
  const int c1 = cols[row * 128 + 64 + lane];
  float s = 0.f;
  if (lane < cn) s += dinv[bsbase + c0];
  if (lane + 64 < cn) s += dinv[bsbase + c1];
  for (int m = 1; m < 64; m <<= 1) s += __shfl_xor(s, m);
  const float d = dinv[row];
  const float S = d * (d + s);
  const int bs = (int)(row >> 10);
  const float2 hw = ((const float2*)hw0s)[bs * 64 + lane];
  const float2 g2 = ((const float2*)gb0)[lane];
  const float2 bg = ((const float2*)bng0)[lane];
  const float2 bb = ((const float2*)bnb0)[lane];
  const float v0 = S * hw.x + (g2.x * kBnScale * bg.x + bb.x);
  const float v1 = S * hw.y + (g2.y * kBnScale * bg.y + bb.y);
  hc0[row * 64 + lane] = (unsigned)f2bf(v0) | ((unsigned)f2bf(v1) << 16);
}

// ---------------------------------------------------------------- QKV GEMM: one A-stage, 3 weight panels -> qkvb [3][N][128] bf16
__global__ __launch_bounds__(256, 2) void k_qkv(const unsigned short* __restrict__ hc,
                                                const unsigned short* __restrict__ WqkvB,
                                                const float* __restrict__ bqkv,
                                                unsigned short* __restrict__ qkvb) {
  __shared__ __align__(16) unsigned short Ab[128 * 128];
  __shared__ __align__(16) unsigned short Bb[128 * 128];
  const int t = threadIdx.x;
  const int cx = (blockIdx.x & 7) * 64 + (blockIdx.x >> 3);  // XCD-chunked
  const long blockRow = (long)cx * 128;
  const int lane = t & 63, w = t >> 6, wr = w >> 1, wc = w & 1;
  const int g = lane >> 4, l15 = lane & 15;
  const f32x4 vzero = {0.f, 0.f, 0.f, 0.f};

#pragma unroll
  for (int i = 0; i < 8; ++i) {
    const int f = (t + i * 256) * 8;
    const unsigned row = f >> 7, k = f & 127;
    *(uint4*)(Ab + (swz(row * 256u + k * 2u, row) >> 1)) = *(const uint4*)(hc + blockRow * 128 + f);
  }

#pragma unroll 1
  for (int pan = 0; pan < 3; ++pan) {
#pragma unroll
    for (int i = 0; i < 8; ++i) {
      const int f = (t + i * 256) * 8;
      const unsigned n = f >> 7, k = f & 127;
      *(uint4*)(Bb + (swz(n * 256u + k * 2u, n) >> 1)) = *(const uint4*)(WqkvB + pan * 16384 + f);
    }
    __syncthreads();

    f32x4 acc[4][4];
#pragma unroll
    for (int a = 0; a < 4; ++a)
#pragma unroll
      for (int b = 0; b < 4; ++b) acc[a][b] = vzero;
#pragma unroll
    for (int kk = 0; kk < 4; ++kk) {
      const unsigned kb = kk * 64u + (unsigned)(g << 4);
      bf16x8 af[4], bfr[4];
#pragma unroll
      for (int mt = 0; mt < 4; ++mt) {
        const unsigned row = wr * 64 + mt * 16 + l15;
        af[mt] = *(const bf16x8*)(Ab + (swz(row * 256u + kb, row) >> 1));
      }
#pragma unroll
      for (int nt = 0; nt < 4; ++nt) {
        const unsigned col = wc * 64 + nt * 16 + l15;
        bfr[nt] = *(const bf16x8*)(Bb + (swz(col * 256u + kb, col) >> 1));
      }
#pragma unroll
      for (int mt = 0; mt < 4; ++mt)
#pragma unroll
        for (int nt = 0; nt < 4; ++nt) acc[mt][nt] = mfma16(af[mt], bfr[nt], acc[mt][nt]);
    }
#pragma unroll
    for (int mt = 0; mt < 4; ++mt)
#pragma unroll
      for (int nt = 0; nt < 4; ++nt)
#pragma unroll
        for (int r = 0; r < 4; ++r) {
          const long gRow = blockRow + wr * 64 + mt * 16 + g * 4 + r;
          const int gCol = wc * 64 + nt * 16 + l15;
          qkvb[(size_t)pan * 8388608 + gRow * 128 + gCol] = f2bf(acc[mt][nt][r] + bqkv[pan * 128 + gCol]);
        }
    __syncthreads();
  }
}

// ---------------------------------------------------------------- SpMM (x4-wide gather): hc = BN(dinv_i*(sum_nbr + self) + gcn_b)
__global__ __launch_bounds__(256) void k_spmm(const uint4* __restrict__ hwp16,
                                              const unsigned short* __restrict__ cols,
                                              const int* __restrict__ cnt, const float* __restrict__ dinv,
                                              const float* __restrict__ gb, const float* __restrict__ bng,
                                              const float* __restrict__ bnb, uint4* __restrict__ hc16) {
  int b = blockIdx.x;
  b = (b & 7) * 2048 + (b >> 3);  // XCD-chunked
  const int w = threadIdx.x >> 6, lane = threadIdx.x & 63;
  const int g = lane >> 4, l15 = lane & 15;
  const long row = (long)b * 4 + w;
  __shared__ unsigned short scol[4][128];
  scol[w][lane] = cols[row * 128 + lane];
  scol[w][lane + 64] = cols[row * 128 + 64 + lane];
  const int cn = cnt[row] < 128 ? cnt[row] : 128;
  const long bsbase = row & ~1023L;
  float acc[8];
#pragma unroll
  for (int e = 0; e < 8; ++e) acc[e] = 0.f;
  if (g == 0) {  // self term, counted once
    const uint4 u = hwp16[row * 16 + l15];
    const unsigned uu[4] = {u.x, u.y, u.z, u.w};
#pragma unroll
    for (int e2 = 0; e2 < 4; ++e2) {
      acc[e2 * 2] += bf2f((unsigned short)uu[e2]);
      acc[e2 * 2 + 1] += bf2f((unsigned short)(uu[e2] >> 16));
    }
  }
  const int cn4 = cn & ~3;
#pragma unroll 2
  for (int i = 0; i < cn4; i += 4) {
    const int j = scol[w][i + g];
    const uint4 u = hwp16[(bsbase + j) * 16 + l15];
    const unsigned uu[4] = {u.x, u.y, u.z, u.w};
#pragma unroll
    for (int e2 = 0; e2 < 4; ++e2) {
      acc[e2 * 2] += bf2f((unsigned short)uu[e2]);
      acc[e2 * 2 + 1] += bf2f((unsigned short)(uu[e2] >> 16));
    }
  }
  if (cn4 + g < cn) {
    const int j = scol[w][cn4 + g];
    const uint4 u = hwp16[(bsbase + j) * 16 + l15];
    const unsigned uu[4] = {u.x, u.y, u.z, u.w};
#pragma unroll
    for (int e2 = 0; e2 < 4; ++e2) {
      acc[e2 * 2] += bf2f((unsigned short)uu[e2]);
      acc[e2 * 2 + 1] += bf2f((unsigned short)(uu[e2] >> 16));
    }
  }
#pragma unroll
  for (int e = 0; e < 8; ++e) {
    acc[e] += __shfl_xor(acc[e], 16);
    acc[e] += __shfl_xor(acc[e], 32);
  }
  if (g == 0) {
    const float di = dinv[row];
    const float4 gv0 = ((const float4*)gb)[l15 * 2], gv1 = ((const float4*)gb)[l15 * 2 + 1];
    const float4 bg0 = ((const float4*)bng)[l15 * 2], bg1 = ((const float4*)bng)[l15 * 2 + 1];
    const float4 bb0 = ((const float4*)bnb)[l15 * 2], bb1 = ((const float4*)bnb)[l15 * 2 + 1];
    float o[8];
    o[0] = (di * acc[0] + gv0.x) * (kBnScale * bg0.x) + bb0.x;
    o[1] = (di * acc[1] + gv0.y) * (kBnScale * bg0.y) + bb0.y;
    o[2] = (di * acc[2] + gv0.z) * (kBnScale * bg0.z) + bb0.z;
    o[3] = (di * acc[3] + gv0.w) * (kBnScale * bg0.w) + bb0.w;
    o[4] = (di * acc[4] + gv1.x) * (kBnScale * bg1.x) + bb1.x;
    o[5] = (di * acc[5] + gv1.y) * (kBnScale * bg1.y) + bb1.y;
    o[6] = (di * acc[6] + gv1.z) * (kBnScale * bg1.z) + bb1.z;
    o[7] = (di * acc[7] + gv1.w) * (kBnScale * bg1.w) + bb1.w;
    uint4 r;
    r.x = (unsigned)f2bf(o[0]) | ((unsigned)f2bf(o[1]) << 16);
    r.y = (unsigned)f2bf(o[2]) | ((unsigned)f2bf(o[3]) << 16);
    r.z = (unsigned)f2bf(o[4]) | ((unsigned)f2bf(o[5]) << 16);
    r.w = (unsigned)f2bf(o[6]) | ((unsigned)f2bf(o[7]) << 16);
    hc16[row * 16 + l15] = r;
  }
}

// ---------------------------------------------------------------- fused attn + Wo/relu/skip + chain GEMM (64 KB LDS, 2 blocks/CU)
// MODE 0: skip = hv;            chain @gW1*dinv -> hwp; write hbufb
// MODE 1: skip = hbufb;         chain @gW2*dinv -> hwp; write hbufb
// MODE 2: skip = hbufb + hv;    chain @Wout+bout, *mask -> ne (+ gpart col-sums)
template <int MODE>
__global__ __launch_bounds__(256, 2) void k_af(
    const unsigned short* __restrict__ qkvb,
    const unsigned short* __restrict__ WoB, const unsigned short* __restrict__ B2,
    const float* __restrict__ bo, const float* __restrict__ hv,
    const float* __restrict__ dinv, const float* __restrict__ bout,
    const float* __restrict__ mask,
    unsigned short* __restrict__ hbufb, unsigned short* __restrict__ hwp,
    float* __restrict__ ne, float* __restrict__ gpart) {
  __shared__ __align__(16) unsigned short sm[32768];  // 64 KB
  unsigned short* Ab = sm;           // attn: vT [head][dh][node]; then aout tile; then T tile
  unsigned short* Bb = sm + 16384;   // attn: per-wave P scratch; then Wo; then B2
  const int t = threadIdx.x, lane = t & 63, hd = t >> 6;
  const int g = lane >> 4, l15 = lane & 15;
  const int c = (blockIdx.x & 7) * 64 + (blockIdx.x >> 3);  // XCD-chunked
  const long cb = (long)c * 128;
  const int bs = (int)(cb >> 10);
  const f32x4 vzero = {0.f, 0.f, 0.f, 0.f};
  const unsigned short* qp = qkvb;
  const unsigned short* kp = qkvb + 8388608;
  const unsigned short* vp = qkvb + 16777216;

  // ---- stage V^T (all threads, all heads)
  {
    const int m = t >> 1, half = t & 1;
    const unsigned short* vrow = vp + (cb + m) * 128 + half * 64;
#pragma unroll
    for (int c8 = 0; c8 < 8; ++c8) {
      const uint4 u = *(const uint4*)(vrow + c8 * 8);
      const int col0 = half * 64 + c8 * 8;
      unsigned short* vb = Ab + (col0 >> 5) * 4096;
      const int dh0 = col0 & 31;
      const unsigned short e[8] = {(unsigned short)u.x, (unsigned short)(u.x >> 16),
                                   (unsigned short)u.y, (unsigned short)(u.y >> 16),
                                   (unsigned short)u.z, (unsigned short)(u.z >> 16),
                                   (unsigned short)u.w, (unsigned short)(u.w >> 16)};
#pragma unroll
      for (int j = 0; j < 8; ++j) {
        const unsigned dh = dh0 + j;
        vb[swz(dh * 256u + (unsigned)m * 2u, dh) >> 1] = e[j];
      }
    }
  }
  bf16x8 kf[8];
#pragma unroll
  for (int nt = 0; nt < 8; ++nt)
    kf[nt] = *(const bf16x8*)(kp + (cb + nt * 16 + l15) * 128 + hd * 32 + (g << 3));
  __syncthreads();

  const unsigned short* vbb = Ab + hd * 4096;
  unsigned short* pb = Bb + hd * 4096;
  const float SC = 0.17677669529663687f * 1.4426950408889634f;  // dh^-0.5 * log2(e)
  unsigned pk[4][2][2][2];  // packed bf16 attn-out [p][mt][nt][r-pair]

#pragma unroll 1
  for (int p = 0; p < 4; ++p) {
    bf16x8 qf[2];
#pragma unroll
    for (int mt = 0; mt < 2; ++mt)
      qf[mt] = *(const bf16x8*)(qp + (cb + p * 32 + mt * 16 + l15) * 128 + hd * 32 + (g << 3));
    f32x4 s[2][8];
#pragma unroll
    for (int mt = 0; mt < 2; ++mt)
#pragma unroll
      for (int nt = 0; nt < 8; ++nt) s[mt][nt] = vzero;
#pragma unroll
    for (int nt = 0; nt < 8; ++nt)
#pragma unroll
      for (int mt = 0; mt < 2; ++mt) s[mt][nt] = mfma16(qf[mt], kf[nt], s[mt][nt]);

    float rinv[2][4];
#pragma unroll
    for (int mt = 0; mt < 2; ++mt) {
#pragma unroll
      for (int r = 0; r < 4; ++r) {
        float mx = s[mt][0][r];
#pragma unroll
        for (int nt = 1; nt < 8; ++nt) mx = fmaxf(mx, s[mt][nt][r]);
#pragma unroll
        for (int msk = 1; msk < 16; msk <<= 1) mx = fmaxf(mx, __shfl_xor(mx, msk));
        const unsigned qpr = mt * 16 + g * 4 + r;
        float sum = 0.f;
#pragma unroll
        for (int nt = 0; nt < 8; ++nt) {
          const float e = exp2f((s[mt][nt][r] - mx) * SC);
          sum += e;
          pb[swz(qpr * 256u + (nt * 16 + l15) * 2u, qpr) >> 1] = f2bf(e);
        }
#pragma unroll
        for (int msk = 1; msk < 16; msk <<= 1) sum += __shfl_xor(sum, msk);
        rinv[mt][r] = 1.0f / sum;
      }
    }

    f32x4 o[2][2];
#pragma unroll
    for (int mt = 0; mt < 2; ++mt)
#pragma unroll
      for (int nt = 0; nt < 2; ++nt) o[mt][nt] = vzero;
#pragma unroll
    for (int kk = 0; kk < 4; ++kk) {
      const unsigned kb = kk * 64u + (unsigned)(g << 4);
      bf16x8 pa[2], vf[2];
#pragma unroll
      for (int mt = 0; mt < 2; ++mt) {
        const unsigned rq = mt * 16 + l15;
        pa[mt] = *(const bf16x8*)(pb + (swz(rq * 256u + kb, rq) >> 1));
      }
#pragma unroll
      for (int nt = 0; nt < 2; ++nt) {
        const unsigned dh = nt * 16 + l15;
        vf[nt] = *(const bf16x8*)(vbb + (swz(dh * 256u + kb, dh) >> 1));
      }
#pragma unroll
      for (int mt = 0; mt < 2; ++mt)
#pragma unroll
        for (int nt = 0; nt < 2; ++nt) o[mt][nt] = mfma16(pa[mt], vf[nt], o[mt][nt]);
    }
#pragma unroll
    for (int mt = 0; mt < 2; ++mt)
#pragma unroll
      for (int nt = 0; nt < 2; ++nt) {
        pk[p][mt][nt][0] = (unsigned)f2bf(o[mt][nt][0] * rinv[mt][0]) |
                           ((unsigned)f2bf(o[mt][nt][1] * rinv[mt][1]) << 16);
        pk[p][mt][nt][1] = (unsigned)f2bf(o[mt][nt][2] * rinv[mt][2]) |
                           ((unsigned)f2bf(o[mt][nt][3] * rinv[mt][3]) << 16);
      }
  }
  __syncthreads();  // attention done: Ab/Bb reusable

  // scatter attn-out -> Ab; stage Wo -> Bb
#pragma unroll
  for (int p = 0; p < 4; ++p)
#pragma unroll
    for (int mt = 0; mt < 2; ++mt)
#pragma unroll
      for (int nt = 0; nt < 2; ++nt)
#pragma unroll
        for (int rr = 0; rr < 2; ++rr) {
          const unsigned u = pk[p][mt][nt][rr];
          const unsigned row0 = p * 32 + mt * 16 + g * 4 + rr * 2;
          const unsigned col = hd * 32 + nt * 16 + l15;
          Ab[swz(row0 * 256u + col * 2u, row0) >> 1] = (unsigned short)u;
          Ab[swz((row0 + 1) * 256u + col * 2u, row0 + 1) >> 1] = (unsigned short)(u >> 16);
        }
#pragma unroll
  for (int i = 0; i < 8; ++i) {
    const int f = (t + i * 256) * 8;
    const unsigned n = f >> 7, k = f & 127;
    *(uint4*)(Bb + (swz(n * 256u + k * 2u, n) >> 1)) = *(const uint4*)(WoB + f);
  }
  __syncthreads();

  // ---- GEMM1: aout @ Wo^T
  const int wr = hd >> 1, wc = hd & 1;
  f32x4 acc[4][4];
#pragma unroll
  for (int a = 0; a < 4; ++a)
#pragma unroll
    for (int b = 0; b < 4; ++b) acc[a][b] = vzero;
#pragma unroll
  for (int kk = 0; kk < 4; ++kk) {
    const unsigned kb = kk * 64u + (unsigned)(g << 4);
    bf16x8 af[4], bfr[4];
#pragma unroll
    for (int mt = 0; mt < 4; ++mt) {
      const unsigned row = wr * 64 + mt * 16 + l15;
      af[mt] = *(const bf16x8*)(Ab + (swz(row * 256u + kb, row) >> 1));
    }
#pragma unroll
    for (int nt = 0; nt < 4; ++nt) {
      const unsigned col = wc * 64 + nt * 16 + l15;
      bfr[nt] = *(const bf16x8*)(Bb + (swz(col * 256u + kb, col) >> 1));
    }
#pragma unroll
    for (int mt = 0; mt < 4; ++mt)
#pragma unroll
      for (int nt = 0; nt < 4; ++nt) acc[mt][nt] = mfma16(af[mt], bfr[nt], acc[mt][nt]);
  }
  __syncthreads();  // done reading Ab/Bb

  // ---- epilogue1: T = skip + relu(acc + bo) -> Ab (bf16); h_new -> hbufb (MODE<2)
  {
    const float b0 = bo[wc * 64 + l15], b1 = bo[wc * 64 + 16 + l15];
    const float b2c = bo[wc * 64 + 32 + l15], b3c = bo[wc * 64 + 48 + l15];
    const float bb[4] = {b0, b1, b2c, b3c};
    float hb[4];
#pragma unroll
    for (int nt = 0; nt < 4; ++nt) hb[nt] = hv[bs * 128 + wc * 64 + nt * 16 + l15];
#pragma unroll
    for (int mt = 0; mt < 4; ++mt)
#pragma unroll
      for (int nt = 0; nt < 4; ++nt)
#pragma unroll
        for (int r = 0; r < 4; ++r) {
          const unsigned row = wr * 64 + mt * 16 + g * 4 + r;
          const long gRow = cb + row;
          const unsigned col = wc * 64 + nt * 16 + l15;
          float v = acc[mt][nt][r] + bb[nt];
          v = v > 0.f ? v : 0.f;
          if constexpr (MODE == 0) {
            v += hb[nt];
          } else {
            v += bf2f(hbufb[gRow * 128 + col]);
            if constexpr (MODE == 2) v += hb[nt];
          }
          const unsigned short vb = f2bf(v);
          if constexpr (MODE < 2) hbufb[gRow * 128 + col] = vb;
          Ab[swz(row * 256u + col * 2u, row) >> 1] = vb;
        }
  }
  // stage B2 -> Bb
  if constexpr (MODE < 2) {
#pragma unroll
    for (int i = 0; i < 8; ++i) {
      const int f = (t + i * 256) * 8;
      const unsigned n = f >> 7, k = f & 127;
      *(uint4*)(Bb + (swz(n * 256u + k * 2u, n) >> 1)) = *(const uint4*)(B2 + f);
    }
  } else {
#pragma unroll
    for (int i = 0; i < 4; ++i) {
      const int f = (t + i * 256) * 8;
      const unsigned n = f >> 7, k = f & 127;
      *(uint4*)(Bb + (swz(n * 256u + k * 2u, n) >> 1)) = *(const uint4*)(B2 + f);
    }
  }
  __syncthreads();

  // ---- GEMM2
  if constexpr (MODE < 2) {
#pragma unroll
    for (int a = 0; a < 4; ++a)
#pragma unroll
      for (int b = 0; b < 4; ++b) acc[a][b] = vzero;
#pragma unroll
    for (int kk = 0; kk < 4; ++kk) {
      const unsigned kb = kk * 64u + (unsigned)(g << 4);
      bf16x8 af[4], bfr[4];
#pragma unroll
      for (int mt = 0; mt < 4; ++mt) {
        const unsigned row = wr * 64 + mt * 16 + l15;
        af[mt] = *(const bf16x8*)(Ab + (swz(row * 256u + kb, row) >> 1));
      }
#pragma unroll
      for (int nt = 0; nt < 4; ++nt) {
        const unsigned col = wc * 64 + nt * 16 + l15;
        bfr[nt] = *(const bf16x8*)(Bb + (swz(col * 256u + kb, col) >> 1));
      }
#pragma unroll
      for (int mt = 0; mt < 4; ++mt)
#pragma unroll
        for (int nt = 0; nt < 4; ++nt) acc[mt][nt] = mfma16(af[mt], bfr[nt], acc[mt][nt]);
    }
#pragma unroll
    for (int mt = 0; mt < 4; ++mt)
#pragma unroll
      for (int nt = 0; nt < 4; ++nt)
#pragma unroll
        for (int r = 0; r < 4; ++r) {
          const long gRow = cb + wr * 64 + mt * 16 + g * 4 + r;
          const unsigned col = wc * 64 + nt * 16 + l15;
          hwp[gRow * 128 + col] = f2bf(acc[mt][nt][r] * dinv[gRow]);
        }
  } else {
    f32x4 acc2[4][2];
#pragma unroll
    for (int a = 0; a < 4; ++a)
#pragma unroll
      for (int b = 0; b < 2; ++b) acc2[a][b] = vzero;
#pragma unroll
    for (int kk = 0; kk < 4; ++kk) {
      const unsigned kb = kk * 64u + (unsigned)(g << 4);
      bf16x8 af[4], bfr[2];
#pragma unroll
      for (int mt = 0; mt < 4; ++mt) {
        const unsigned row = wr * 64 + mt * 16 + l15;
        af[mt] = *(const bf16x8*)(Ab + (swz(row * 256u + kb, row) >> 1));
      }
#pragma unroll
      for (int nt = 0; nt < 2; ++nt) {
        const unsigned col = wc * 32 + nt * 16 + l15;
        bfr[nt] = *(const bf16x8*)(Bb + (swz(col * 256u + kb, col) >> 1));
      }
#pragma unroll
      for (int mt = 0; mt < 4; ++mt)
#pragma unroll
        for (int nt = 0; nt < 2; ++nt) acc2[mt][nt] = mfma16(af[mt], bfr[nt], acc2[mt][nt]);
    }
    const float mk = mask[bs];
#pragma unroll
    for (int nt = 0; nt < 2; ++nt) {
      const unsigned col = wc * 32 + nt * 16 + l15;
      const float b2 = bout[col];
      float csum = 0.f;
#pragma unroll
      for (int mt = 0; mt < 4; ++mt)
#pragma unroll
        for (int r = 0; r < 4; ++r) {
          const long gRow = cb + wr * 64 + mt * 16 + g * 4 + r;
          const float v = (acc2[mt][nt][r] + b2) * mk;
          ne[gRow * 64 + col] = v;
          csum += v;
        }
      csum += __shfl_xor(csum, 16);
      csum += __shfl_xor(csum, 32);
      if (g == 0) gpart[((long)c * 2 + wr) * 64 + col] = csum;
    }
  }
}

// ---------------------------------------------------------------- graph mean finish: ge = sum(gpart)/1024
__global__ void k_gfin(const float* __restrict__ gpart, float* __restrict__ ge) {
  const int tid = blockIdx.x * 256 + threadIdx.x;
  if (tid >= 4096) return;
  const int bs = tid >> 6, col = tid & 63;
  float s = 0.f;
#pragma unroll
  for (int q = 0; q < 16; ++q) s += gpart[(bs * 16 + q) * 64 + col];
  ge[tid] = s * (1.0f / 1024.0f);
}

// ----------------------------------------------------------------
extern "C" void kernel_launch(void* const* d_in, const int* in_sizes, int n_in,
                              void* d_out, int out_size, void* d_ws, size_t ws_size,
                              hipStream_t stream) {
  const float* x = (const float*)d_in[0];
  const float* adj = (const float*)d_in[1];
  const float* mask = (const float*)d_in[2];
  const float* fi = (const float*)d_in[3];
  const float* Win = (const float*)d_in[4];
  const float* bin = (const float*)d_in[5];
  const float* lng = (const float*)d_in[6];
  const float* lnb = (const float*)d_in[7];
  const float* gW = (const float*)d_in[8];
  const float* gB = (const float*)d_in[9];
  const float* bng = (const float*)d_in[10];
  const float* bnb = (const float*)d_in[11];
  const float* Wqkv = (const float*)d_in[12];
  const float* bqkv = (const float*)d_in[13];
  const float* Wo = (const float*)d_in[14];
  const float* bo = (const float*)d_in[15];
  const float* Wout = (const float*)d_in[16];
  const float* bout = (const float*)d_in[17];

  char* ws = (char*)d_ws;
  float* dinv = (float*)ws;                    ws += 65536 * 4;
  int* cnt = (int*)ws;                         ws += 65536 * 4;
  float* hv = (float*)ws;                      ws += 64 * 128 * 4;
  float* hw0s = (float*)ws;                    ws += 64 * 128 * 4;
  float* gpart = (float*)ws;                   ws += 1024 * 64 * 4;
  unsigned short* WqkvB = (unsigned short*)ws; ws += 49152 * 2;
  unsigned short* WoB = (unsigned short*)ws;   ws += 16384 * 2;
  unsigned short* gWB = (unsigned short*)ws;   ws += 49152 * 2;
  unsigned short* WoutB = (unsigned short*)ws; ws += 8192 * 2;
  unsigned short* cols = (unsigned short*)ws;  ws += (size_t)65536 * 128 * 2;
  unsigned short* hbufb = (unsigned short*)ws; ws += (size_t)65536 * 128 * 2;
  unsigned short* hwp = (unsigned short*)ws;   ws += (size_t)65536 * 128 * 2;
  unsigned short* hc = (unsigned short*)ws;    ws += (size_t)65536 * 128 * 2;
  unsigned short* qkvb = (unsigned short*)ws;  ws += (size_t)65536 * 384 * 2;

  float* ne = (float*)d_out;
  float* ge = ne + (size_t)4194304;

  k_pre<<<16928, 256, 0, stream>>>(adj, cols, cnt, dinv, x, fi, Win, bin, lng, lnb,
                                   gW, bng, hv, hw0s, Wqkv, Wo, Wout,
                                   WqkvB, WoB, gWB, WoutB);
  k_scal2<<<16384, 256, 0, stream>>>(cols, cnt, dinv, hw0s, gB, bng, bnb, (unsigned*)hc);

  // layer 0
  k_qkv<<<512, 256, 0, stream>>>(hc, WqkvB, bqkv, qkvb);
  k_af<0><<<512, 256, 0, stream>>>(qkvb, WoB, gWB + 16384, bo, hv, dinv, nullptr, nullptr,
                                   hbufb, hwp, nullptr, nullptr);
  // layer 1
  k_spmm<<<16384, 256, 0, stream>>>((const uint4*)hwp, cols, cnt, dinv,
                                    gB + 128, bng + 128, bnb + 128, (uint4*)hc);
  k_qkv<<<512, 256, 0, stream>>>(hc, WqkvB, bqkv, qkvb);
  k_af<1><<<512, 256, 0, stream>>>(qkvb, WoB, gWB + 32768, bo, hv, dinv, nullptr, nullptr,
                                   hbufb, hwp, nullptr, nullptr);
  // layer 2
  k_spmm<<<16384, 256, 0, stream>>>((const uint4*)hwp, cols, cnt, dinv,
                                    gB + 256, bng + 256, bnb + 256, (uint4*)hc);
  k_qkv<<<512, 256, 0, stream>>>(hc, WqkvB, bqkv, qkvb);
  k_af<2><<<512, 256, 0, stream>>>(qkvb, WoB, WoutB, bo, hv, dinv, bout, mask,
                                   hbufb, nullptr, ne, gpart);

  k_gfin<<<16, 256, 0, stream>>>(gpart, ge);
}